// Round 12
// baseline (853.962 us; speedup 1.0000x reference)
//
#include <hip/hip_runtime.h>
#include <hip/hip_bf16.h>

typedef unsigned short u16;
typedef unsigned int u32;
typedef __attribute__((ext_vector_type(8))) short short8;   // 8 bf16 (4 VGPRs)
typedef __attribute__((ext_vector_type(4))) float f32x4;    // MFMA accumulator

#define DEV static __device__ __forceinline__

DEV u16 f2bf(float x){
  union { __hip_bfloat16 b; u16 u; } c;
  c.b = __float2bfloat16(x);   // RNE
  return c.u;
}
DEV float bf2f(u16 u){
  union { float f; unsigned i; } c;
  c.i = ((unsigned)u) << 16;
  return c.f;
}
DEV u32 pk2(float lo, float hi){          // bf16x2: low half = lo
  return ((u32)f2bf(hi) << 16) | (u32)f2bf(lo);
}

DEV void gload16(const void* g, void* lds){
  __builtin_amdgcn_global_load_lds((const __attribute__((address_space(1))) void*)g,
                                   (__attribute__((address_space(3))) void*)lds, 16, 0, 0);
}

// ---------------------------------------------------------------------------
// Weight convert + transpose: src fp32 [K=256][N] -> dst bf16 [N][256]
// ---------------------------------------------------------------------------
__global__ __launch_bounds__(512)
void wconv_kernel(const float* __restrict__ Wq, const float* __restrict__ Wk,
                  const float* __restrict__ Wv, const float* __restrict__ Wo,
                  const float* __restrict__ W1, const float* __restrict__ W2,
                  const float* __restrict__ Wh,
                  u16* __restrict__ WqkvT, u16* __restrict__ WoT,
                  u16* __restrict__ W1T, u16* __restrict__ W2T, u16* __restrict__ WhT)
{
  __shared__ float tile[64][65];
  const int j = blockIdx.y;
  int N = 256;
  const float* src; u16* dst;
  if (j < 48){
    const int li = j / 6, t = j % 6;
    switch(t){
      case 0:  src = Wq + li*65536; dst = WqkvT + li*196608;          break;
      case 1:  src = Wk + li*65536; dst = WqkvT + li*196608 + 65536;  break;
      case 2:  src = Wv + li*65536; dst = WqkvT + li*196608 + 131072; break;
      case 3:  src = Wo + li*65536; dst = WoT  + li*65536;            break;
      case 4:  src = W1 + li*65536; dst = W1T  + li*65536;            break;
      default: src = W2 + li*65536; dst = W2T  + li*65536;            break;
    }
  } else { N = 512; src = Wh; dst = WhT; }
  const int tilesPerRow = N >> 6;
  if ((int)blockIdx.x >= tilesPerRow * 4) return;
  const int tx = blockIdx.x % tilesPerRow, ty = blockIdx.x / tilesPerRow;
  const int tid = threadIdx.x;
  #pragma unroll
  for (int i=0;i<2;++i){
    const int e = tid + i*512;
    const int r = e >> 4, cq = (e & 15)*4;
    float4 v = *(const float4*)(src + (size_t)(ty*64 + r)*N + tx*64 + cq);
    tile[r][cq+0]=v.x; tile[r][cq+1]=v.y; tile[r][cq+2]=v.z; tile[r][cq+3]=v.w;
  }
  __syncthreads();
  #pragma unroll
  for (int i=0;i<2;++i){
    const int e = tid + i*512;
    const int orow = e >> 4, tq = (e & 15)*4;
    ushort4 o;
    o.x = f2bf(tile[tq+0][orow]); o.y = f2bf(tile[tq+1][orow]);
    o.z = f2bf(tile[tq+2][orow]); o.w = f2bf(tile[tq+3][orow]);
    *(ushort4*)(dst + (size_t)(tx*64 + orow)*256 + ty*64 + tq) = o;
  }
}

// ---------------------------------------------------------------------------
// Embedding + positional encoding + LN1(layer0): one wave per row.
// ---------------------------------------------------------------------------
__global__ __launch_bounds__(256)
void embed_ln_kernel(const int* __restrict__ idx, const float* __restrict__ emb,
                     const float* __restrict__ g, const float* __restrict__ be,
                     u16* __restrict__ x, u16* __restrict__ hb)
{
  const int tid = threadIdx.x;
  const int w = tid >> 6, l = tid & 63;
  const int row = blockIdx.x*4 + w;
  const int t = row & 255;
  const int v = idx[row];
  const int c4 = l*4;
  float4 e = *(const float4*)(emb + (size_t)v*256 + c4);
  float r[4];
  const float ef[4] = {e.x, e.y, e.z, e.w};
  #pragma unroll
  for (int i=0;i<4;++i){
    const int c = c4 + i;
    const float div = expf((float)(c & ~1) * (-9.210340371976184f/256.f));
    const float ang = (float)t * div;
    r[i] = ((c & 1) ? cosf(ang) : sinf(ang)) + ef[i];
  }
  ushort4 xo;
  xo.x = f2bf(r[0]); xo.y = f2bf(r[1]); xo.z = f2bf(r[2]); xo.w = f2bf(r[3]);
  *(ushort4*)(x + (size_t)row*256 + c4) = xo;
  float s = r[0]+r[1]+r[2]+r[3];
  float q = r[0]*r[0]+r[1]*r[1]+r[2]*r[2]+r[3]*r[3];
  #pragma unroll
  for (int m=32; m; m>>=1){ s += __shfl_xor(s,m); q += __shfl_xor(q,m); }
  const float mu = s * (1.f/256.f);
  const float var = q * (1.f/256.f) - mu*mu;
  const float rstd = rsqrtf(var + 1e-5f);
  const float4 gv = *(const float4*)(g + c4);
  const float4 bv = *(const float4*)(be + c4);
  ushort4 o;
  o.x = f2bf((r[0]-mu)*rstd*gv.x + bv.x);
  o.y = f2bf((r[1]-mu)*rstd*gv.y + bv.y);
  o.z = f2bf((r[2]-mu)*rstd*gv.z + bv.z);
  o.w = f2bf((r[3]-mu)*rstd*gv.w + bv.w);
  *(ushort4*)(hb + (size_t)row*256 + c4) = o;
}

// ---------------------------------------------------------------------------
// Wide GEMM: 128x256 tile, 512 threads / 8 waves (2m x 4n, wave 64x64).
// C[M][N] = A[M][256] @ W^T[N][256]. 2-phase dbuf, 48 KB LDS.
// Per kt: 1 A-gload + 2 B-gloads per thread; 16 MFMA per wave.
// ---------------------------------------------------------------------------
template<bool OBF, bool RELU_, bool BIAS_>
__global__ __launch_bounds__(512, 4)
void gemm512_kernel(const u16* __restrict__ A, const u16* __restrict__ W,
                    const float* __restrict__ bias, void* __restrict__ Cv, int ldC)
{
  __shared__ __align__(16) u16 Al[2][4096];   // [128][32]
  __shared__ __align__(16) u16 Bl[2][8192];   // [256][32]
  const int tid = threadIdx.x;
  const int w = tid >> 6, l = tid & 63;
  const int lr = l & 15, lg = l >> 4;
  const int m0 = blockIdx.x * 128, n0 = blockIdx.y * 256;
  const int wm = w >> 2, wn = w & 3;
  const int rowc = l >> 2;
  const int pswz = (l & 3) ^ ((l >> 3) & 3);

  f32x4 acc[4][4];
  #pragma unroll
  for (int i=0;i<4;++i)
    #pragma unroll
    for (int jn=0;jn<4;++jn) acc[i][jn] = (f32x4){0.f,0.f,0.f,0.f};

  gload16(A + (size_t)(m0 + 16*w + rowc)*256 + pswz*8, &Al[0][w*512]);
  #pragma unroll
  for (int it=0; it<2; ++it){
    const int c = w + it*8;
    gload16(W + (size_t)(n0 + 16*c + rowc)*256 + pswz*8, &Bl[0][c*512]);
  }
  __syncthreads();

  for (int kt=0; kt<8; ++kt){
    if (kt < 7){
      const int kofs = (kt+1) * 32, nb = (kt+1) & 1;
      gload16(A + (size_t)(m0 + 16*w + rowc)*256 + kofs + pswz*8, &Al[nb][w*512]);
      #pragma unroll
      for (int it=0; it<2; ++it){
        const int c = w + it*8;
        gload16(W + (size_t)(n0 + 16*c + rowc)*256 + kofs + pswz*8, &Bl[nb][c*512]);
      }
    }
    const int buf = kt & 1;
    short8 af[4], bf[4];
    #pragma unroll
    for (int mt=0; mt<4; ++mt){
      const int row = wm*64 + mt*16 + lr;
      const int kb = (lg*16) ^ ((((row>>1)&3))<<4);
      af[mt] = *(const short8*)((const char*)Al[buf] + row*64 + kb);
    }
    #pragma unroll
    for (int nt=0; nt<4; ++nt){
      const int row = wn*64 + nt*16 + lr;
      const int kb = (lg*16) ^ ((((row>>1)&3))<<4);
      bf[nt] = *(const short8*)((const char*)Bl[buf] + row*64 + kb);
    }
    #pragma unroll
    for (int mt=0; mt<4; ++mt)
      #pragma unroll
      for (int nt=0; nt<4; ++nt)
        acc[mt][nt] = __builtin_amdgcn_mfma_f32_16x16x32_bf16(af[mt], bf[nt], acc[mt][nt], 0,0,0);
    __syncthreads();
  }

  #pragma unroll
  for (int nt=0; nt<4; ++nt){
    const int col = n0 + wn*64 + nt*16 + lr;
    const float bv = BIAS_ ? bias[col] : 0.f;
    #pragma unroll
    for (int mt=0; mt<4; ++mt){
      f32x4 v = acc[mt][nt];
      #pragma unroll
      for (int r=0;r<4;++r){
        const int row = m0 + wm*64 + mt*16 + lg*4 + r;
        float val = v[r] + bv;
        if (RELU_) val = fmaxf(val, 0.f);
        if (OBF) ((u16*)Cv)[(size_t)row*ldC + col] = f2bf(val);
        else     ((float*)Cv)[(size_t)row*ldC + col] = val;
      }
    }
  }
}

// ---------------------------------------------------------------------------
// GEMM + residual + LayerNorm epilogue. Block = 64 full rows (grid 512).
// Residual stream bf16; adds in f32.
// ---------------------------------------------------------------------------
__global__ __launch_bounds__(256, 2)
void gemm_res_ln_kernel(const u16* __restrict__ A, const u16* __restrict__ W,
                        const float* __restrict__ bias,
                        const float* __restrict__ g, const float* __restrict__ be,
                        u16* __restrict__ x, u16* __restrict__ hb)
{
  __shared__ __align__(16) u16 Al[2][2048];   // [64][32]
  __shared__ __align__(16) u16 Bl[2][8192];   // [256][32]
  __shared__ float sS[64][2], sQ[64][2];
  const int tid = threadIdx.x;
  const int w = tid >> 6, l = tid & 63;
  const int lr = l & 15, lg = l >> 4;
  const int m0 = blockIdx.x * 64;
  const int wm = w >> 1, wn = w & 1;
  const int rowc = l >> 2;
  const int pswz = (l & 3) ^ ((l >> 3) & 3);

  f32x4 acc[2][2][4];
  #pragma unroll
  for (int p=0;p<2;++p)
    #pragma unroll
    for (int i=0;i<2;++i)
      #pragma unroll
      for (int jn=0;jn<4;++jn) acc[p][i][jn] = (f32x4){0.f,0.f,0.f,0.f};

  gload16(A + (size_t)(m0 + 16*w + rowc)*256 + pswz*8, &Al[0][w*512]);
  #pragma unroll
  for (int cc=0; cc<4; ++cc){
    const int c = w + cc*4;
    gload16(W + (size_t)(16*c + rowc)*256 + pswz*8, &Bl[0][c*512]);
  }
  __syncthreads();

  for (int kt=0; kt<8; ++kt){
    if (kt < 7){
      const int kofs = (kt+1)*32, nb = (kt+1)&1;
      gload16(A + (size_t)(m0 + 16*w + rowc)*256 + kofs + pswz*8, &Al[nb][w*512]);
      #pragma unroll
      for (int cc=0; cc<4; ++cc){
        const int c = w + cc*4;
        gload16(W + (size_t)(16*c + rowc)*256 + kofs + pswz*8, &Bl[nb][c*512]);
      }
    }
    const int buf = kt & 1;
    short8 af[2], bf[2][4];
    #pragma unroll
    for (int mt=0; mt<2; ++mt){
      const int row = wm*32 + mt*16 + lr;
      const int kb = (lg*16) ^ ((((row>>1)&3))<<4);
      af[mt] = *(const short8*)((const char*)Al[buf] + row*64 + kb);
    }
    #pragma unroll
    for (int p=0; p<2; ++p)
      #pragma unroll
      for (int nt=0; nt<4; ++nt){
        const int brow = p*128 + wn*64 + nt*16 + lr;
        const int kb = (lg*16) ^ ((((brow>>1)&3))<<4);
        bf[p][nt] = *(const short8*)((const char*)Bl[buf] + brow*64 + kb);
      }
    #pragma unroll
    for (int p=0; p<2; ++p)
      #pragma unroll
      for (int mt=0; mt<2; ++mt)
        #pragma unroll
        for (int nt=0; nt<4; ++nt)
          acc[p][mt][nt] = __builtin_amdgcn_mfma_f32_16x16x32_bf16(af[mt], bf[p][nt], acc[p][mt][nt], 0,0,0);
    __syncthreads();
  }

  float bcol[2][4], gcol[2][4], becol[2][4];
  #pragma unroll
  for (int p=0;p<2;++p)
    #pragma unroll
    for (int nt=0;nt<4;++nt){
      const int col = p*128 + wn*64 + nt*16 + lr;
      bcol[p][nt] = bias[col]; gcol[p][nt] = g[col]; becol[p][nt] = be[col];
    }
  float s8[2][4], q8[2][4];
  #pragma unroll
  for (int mt=0;mt<2;++mt)
    #pragma unroll
    for (int rr=0;rr<4;++rr){ s8[mt][rr]=0.f; q8[mt][rr]=0.f; }

  #pragma unroll
  for (int p=0;p<2;++p)
    #pragma unroll
    for (int mt=0;mt<2;++mt)
      #pragma unroll
      for (int nt=0;nt<4;++nt)
        #pragma unroll
        for (int rr=0;rr<4;++rr){
          const int row = m0 + wm*32 + mt*16 + lg*4 + rr;
          const int col = p*128 + wn*64 + nt*16 + lr;
          float val = acc[p][mt][nt][rr] + bcol[p][nt] + bf2f(x[(size_t)row*256 + col]);
          x[(size_t)row*256 + col] = f2bf(val);
          val = bf2f(f2bf(val));     // keep stats consistent with stored bf16
          acc[p][mt][nt][rr] = val;
          s8[mt][rr] += val; q8[mt][rr] += val*val;
        }
  #pragma unroll
  for (int mt=0;mt<2;++mt)
    #pragma unroll
    for (int rr=0;rr<4;++rr){
      #pragma unroll
      for (int m=1; m<16; m<<=1){
        s8[mt][rr] += __shfl_xor(s8[mt][rr], m);
        q8[mt][rr] += __shfl_xor(q8[mt][rr], m);
      }
      if (lr == 0){
        const int lrow = wm*32 + mt*16 + lg*4 + rr;
        sS[lrow][wn] = s8[mt][rr]; sQ[lrow][wn] = q8[mt][rr];
      }
    }
  __syncthreads();

  #pragma unroll
  for (int mt=0;mt<2;++mt)
    #pragma unroll
    for (int rr=0;rr<4;++rr){
      const int lrow = wm*32 + mt*16 + lg*4 + rr;
      const float mu = (sS[lrow][0] + sS[lrow][1]) * (1.f/256.f);
      const float var = (sQ[lrow][0] + sQ[lrow][1]) * (1.f/256.f) - mu*mu;
      const float rstd = rsqrtf(var + 1e-5f);
      #pragma unroll
      for (int p=0;p<2;++p)
        #pragma unroll
        for (int nt=0;nt<4;++nt){
          const int col = p*128 + wn*64 + nt*16 + lr;
          const float out = (acc[p][mt][nt][rr] - mu)*rstd*gcol[p][nt] + becol[p][nt];
          hb[(size_t)(m0+lrow)*256 + col] = f2bf(out);
        }
    }
}

// ---------------------------------------------------------------------------
// Fused causal attention, one block per (b,h): 8 waves x 512 threads.
// SWAPPED QK^T (S^T tile, q = lane column) => in-lane softmax.
// PV A-fragment built in-register via bf16x2 pack + 4-lane-group shfl.
// ---------------------------------------------------------------------------
__global__ __launch_bounds__(512, 4)
void attn_kernel(const u16* __restrict__ qkv, u16* __restrict__ att)
{
  __shared__ __align__(16) u16 sK[16384];   // [256 t][64 d] swz (row 128B)
  __shared__ __align__(16) u16 sV[16384];   // [64 hd][256 t] swz (row 512B)
  const int bh = blockIdx.x;
  const int b = bh >> 2, h = bh & 3;
  const int tid = threadIdx.x;
  const int w = tid >> 6, l = tid & 63, lr = l & 15, lg = l >> 4;
  const u16* base = qkv + (size_t)(b*256)*768;

  #pragma unroll
  for (int it=0; it<4; ++it){
    const int c = tid + it*512;
    const int t = c >> 3, p = c & 7;
    uint4 val = *(const uint4*)(base + (size_t)t*768 + 256 + h*64 + p*8);
    *(uint4*)((char*)sK + t*128 + ((p*16) ^ ((t&7)<<4))) = val;
  }
  #pragma unroll
  for (int it=0; it<8; ++it){
    const int c = tid + it*512;
    const int t = c >> 4, hdq = c & 15;
    ushort4 v = *(const ushort4*)(base + (size_t)t*768 + 512 + h*64 + hdq*4);
    #pragma unroll
    for (int j=0;j<4;++j){
      const int hd = hdq*4 + j;
      *(u16*)((char*)sV + hd*512 + ((t*2) ^ ((hd&31)<<4))) = ((const u16*)&v)[j];
    }
  }
  __syncthreads();

  u16* ab = att + (size_t)(b*256)*256 + h*64;
  const float c1 = 0.09016844005556021f;   // (1/16) * log2(e)
  const int srcA = lr + (lg & 1)*32;
  const int srcB = srcA + 16;
  const bool selB = (lg >> 1) != 0;

  #pragma unroll
  for (int ph=0; ph<2; ++ph){
    const int rt = ph ? (15 - w) : w;
    const u16* qp = base + (size_t)(rt*16 + lr)*768 + h*64;
    const short8 qf0 = *(const short8*)(qp + lg*8);
    const short8 qf1 = *(const short8*)(qp + 32 + lg*8);

    f32x4 acc[16];
    #pragma unroll
    for (int nt=0; nt<16; ++nt) acc[nt] = (f32x4){0.f,0.f,0.f,0.f};
    #pragma unroll
    for (int nt=0; nt<16; ++nt){
      if (nt <= rt){
        const int row = nt*16 + lr;
        const int swz = (row & 7) << 4;
        short8 k0 = *(const short8*)((const char*)sK + row*128 + ((lg*16) ^ swz));
        short8 k1 = *(const short8*)((const char*)sK + row*128 + ((64 + lg*16) ^ swz));
        acc[nt] = __builtin_amdgcn_mfma_f32_16x16x32_bf16(k0, qf0, acc[nt], 0,0,0);
        acc[nt] = __builtin_amdgcn_mfma_f32_16x16x32_bf16(k1, qf1, acc[nt], 0,0,0);
      }
    }
    #pragma unroll
    for (int nt=0; nt<16; ++nt){
      if (nt == rt){
        #pragma unroll
        for (int r=0;r<4;++r)
          acc[nt][r] = (lg*4 + r > lr) ? -3.0e38f : acc[nt][r];
      }
    }

    float m_ = -3.0e38f;
    #pragma unroll
    for (int nt=0; nt<16; ++nt){
      if (nt <= rt){
        float t01 = fmaxf(acc[nt][0], acc[nt][1]);
        float t23 = fmaxf(acc[nt][2], acc[nt][3]);
        m_ = fmaxf(m_, fmaxf(t01, t23));
      }
    }
    m_ = fmaxf(m_, __shfl_xor(m_, 16));
    m_ = fmaxf(m_, __shfl_xor(m_, 32));
    const float mm = m_ * c1;
    float s_ = 0.f;
    #pragma unroll
    for (int nt=0; nt<16; ++nt){
      if (nt <= rt){
        #pragma unroll
        for (int r=0;r<4;++r){
          const float p = exp2f(fmaf(acc[nt][r], c1, -mm));
          acc[nt][r] = p;
          s_ += p;
        }
      }
    }
    s_ += __shfl_xor(s_, 16);
    s_ += __shfl_xor(s_, 32);
    const float inv = 1.f / s_;

    f32x4 oacc[4];
    #pragma unroll
    for (int nt=0; nt<4; ++nt) oacc[nt] = (f32x4){0.f,0.f,0.f,0.f};
    #pragma unroll
    for (int tc=0; tc<8; ++tc){
      if (tc <= (rt >> 1)){
        const int nt0 = 2*tc, nt1 = 2*tc+1;
        const float p00 = acc[nt0][0]*inv, p01 = acc[nt0][1]*inv;
        const float p02 = acc[nt0][2]*inv, p03 = acc[nt0][3]*inv;
        const float p10 = (nt1 <= rt) ? acc[nt1][0]*inv : 0.f;
        const float p11 = (nt1 <= rt) ? acc[nt1][1]*inv : 0.f;
        const float p12 = (nt1 <= rt) ? acc[nt1][2]*inv : 0.f;
        const float p13 = (nt1 <= rt) ? acc[nt1][3]*inv : 0.f;
        const u32 A0 = pk2(p00,p01), A1 = pk2(p02,p03);
        const u32 B0 = pk2(p10,p11), B1 = pk2(p12,p13);
        const u32 a0A = __shfl((int)A0, srcA), a0B = __shfl((int)B0, srcA);
        const u32 a1A = __shfl((int)A1, srcA), a1B = __shfl((int)B1, srcA);
        const u32 a2A = __shfl((int)A0, srcB), a2B = __shfl((int)B0, srcB);
        const u32 a3A = __shfl((int)A1, srcB), a3B = __shfl((int)B1, srcB);
        union { u32 u[4]; short8 s; } apu;
        apu.u[0] = selB ? a0B : a0A;
        apu.u[1] = selB ? a1B : a1A;
        apu.u[2] = selB ? a2B : a2A;
        apu.u[3] = selB ? a3B : a3A;
        const short8 ap = apu.s;
        #pragma unroll
        for (int nt=0; nt<4; ++nt){
          const int vrow = nt*16 + lr;
          const short8 bv = *(const short8*)((const char*)sV + vrow*512 +
                               ((tc*64 + lg*16) ^ ((vrow&31)<<4)));
          oacc[nt] = __builtin_amdgcn_mfma_f32_16x16x32_bf16(ap, bv, oacc[nt], 0,0,0);
        }
      }
    }

    #pragma unroll
    for (int nt=0; nt<4; ++nt)
      #pragma unroll
      for (int r=0;r<4;++r){
        const int row = rt*16 + lg*4 + r;
        ab[(size_t)row*256 + nt*16 + lr] = f2bf(oacc[nt][r]);
      }
  }
}

// ---------------------------------------------------------------------------
extern "C" void kernel_launch(void* const* d_in, const int* in_sizes, int n_in,
                              void* d_out, int out_size, void* d_ws, size_t ws_size,
                              hipStream_t stream)
{
  (void)in_sizes; (void)n_in; (void)out_size; (void)ws_size;
  const int*   idx = (const int*)  d_in[0];
  const float* tok = (const float*)d_in[1];
  const float* Wq  = (const float*)d_in[2];
  const float* Wk  = (const float*)d_in[3];
  const float* Wv  = (const float*)d_in[4];
  const float* Wo  = (const float*)d_in[5];
  const float* bo  = (const float*)d_in[6];
  const float* W1  = (const float*)d_in[7];
  const float* b1  = (const float*)d_in[8];
  const float* W2  = (const float*)d_in[9];
  const float* b2  = (const float*)d_in[10];
  const float* g1  = (const float*)d_in[11];
  const float* be1 = (const float*)d_in[12];
  const float* g2  = (const float*)d_in[13];
  const float* be2 = (const float*)d_in[14];
  const float* gf  = (const float*)d_in[15];
  const float* bfi = (const float*)d_in[16];
  const float* Wh  = (const float*)d_in[17];
  const float* bh  = (const float*)d_in[18];

  char* ws = (char*)d_ws;
  u16*   x    = (u16*)ws;    ws += (size_t)32768*256*2;   // residual stream bf16
  u16*   hb   = (u16*)ws;    ws += (size_t)32768*256*2;   // LN output bf16
  u16*   mid  = (u16*)ws;    ws += (size_t)32768*256*2;   // FFN mid bf16
  u16*   qkv  = (u16*)ws;    ws += (size_t)32768*768*2;
  u16*   att  = (u16*)ws;    ws += (size_t)32768*256*2;   // attn out bf16
  u16*   WqkvT= (u16*)ws;    ws += (size_t)8*768*256*2;
  u16*   WoT  = (u16*)ws;    ws += (size_t)8*256*256*2;
  u16*   W1T  = (u16*)ws;    ws += (size_t)8*256*256*2;
  u16*   W2T  = (u16*)ws;    ws += (size_t)8*256*256*2;
  u16*   WhT  = (u16*)ws;    ws += (size_t)512*256*2;

  wconv_kernel<<<dim3(32,49),512,0,stream>>>(Wq,Wk,Wv,Wo,W1,W2,Wh,WqkvT,WoT,W1T,W2T,WhT);
  embed_ln_kernel<<<8192,256,0,stream>>>(idx, tok, g1, be1, x, hb);
  for (int l=0; l<8; ++l){
    gemm512_kernel<true,false,false><<<dim3(256,3),512,0,stream>>>(
        hb, WqkvT + (size_t)l*196608, nullptr, qkv, 768);
    attn_kernel<<<512,512,0,stream>>>(qkv, att);
    gemm_res_ln_kernel<<<512,256,0,stream>>>(
        att, WoT + (size_t)l*65536, bo + l*256, g2 + l*256, be2 + l*256, x, hb);
    gemm512_kernel<true,true,true><<<dim3(256,1),512,0,stream>>>(
        hb, W1T + (size_t)l*65536, b1 + l*256, mid, 256);
    const float* gn = (l < 7) ? (g1 + (l+1)*256) : gf;
    const float* bn = (l < 7) ? (be1 + (l+1)*256) : bfi;
    gemm_res_ln_kernel<<<512,256,0,stream>>>(
        mid, W2T + (size_t)l*65536, b2 + l*256, gn, bn, x, hb);
  }
  gemm512_kernel<false,false,true><<<dim3(256,2),512,0,stream>>>(
      hb, WhT, bh, (float*)d_out, 512);
}

// Round 13
// 801.746 us; speedup vs baseline: 1.0651x; 1.0651x over previous
//
#include <hip/hip_runtime.h>
#include <hip/hip_bf16.h>

typedef unsigned short u16;
typedef unsigned int u32;
typedef __attribute__((ext_vector_type(8))) short short8;   // 8 bf16 (4 VGPRs)
typedef __attribute__((ext_vector_type(4))) float f32x4;    // MFMA accumulator

#define DEV static __device__ __forceinline__

DEV u16 f2bf(float x){
  union { __hip_bfloat16 b; u16 u; } c;
  c.b = __float2bfloat16(x);   // RNE
  return c.u;
}
DEV float bf2f(u16 u){
  union { float f; unsigned i; } c;
  c.i = ((unsigned)u) << 16;
  return c.f;
}
DEV u32 pk2(float lo, float hi){          // bf16x2: low half = lo
  return ((u32)f2bf(hi) << 16) | (u32)f2bf(lo);
}

DEV void gload16(const void* g, void* lds){
  __builtin_amdgcn_global_load_lds((const __attribute__((address_space(1))) void*)g,
                                   (__attribute__((address_space(3))) void*)lds, 16, 0, 0);
}

// ---------------------------------------------------------------------------
// Weight convert + transpose: src fp32 [K=256][N] -> dst bf16 [N][256]
// ---------------------------------------------------------------------------
__global__ __launch_bounds__(512)
void wconv_kernel(const float* __restrict__ Wq, const float* __restrict__ Wk,
                  const float* __restrict__ Wv, const float* __restrict__ Wo,
                  const float* __restrict__ W1, const float* __restrict__ W2,
                  const float* __restrict__ Wh,
                  u16* __restrict__ WqkvT, u16* __restrict__ WoT,
                  u16* __restrict__ W1T, u16* __restrict__ W2T, u16* __restrict__ WhT)
{
  __shared__ float tile[64][65];
  const int j = blockIdx.y;
  int N = 256;
  const float* src; u16* dst;
  if (j < 48){
    const int li = j / 6, t = j % 6;
    switch(t){
      case 0:  src = Wq + li*65536; dst = WqkvT + li*196608;          break;
      case 1:  src = Wk + li*65536; dst = WqkvT + li*196608 + 65536;  break;
      case 2:  src = Wv + li*65536; dst = WqkvT + li*196608 + 131072; break;
      case 3:  src = Wo + li*65536; dst = WoT  + li*65536;            break;
      case 4:  src = W1 + li*65536; dst = W1T  + li*65536;            break;
      default: src = W2 + li*65536; dst = W2T  + li*65536;            break;
    }
  } else { N = 512; src = Wh; dst = WhT; }
  const int tilesPerRow = N >> 6;
  if ((int)blockIdx.x >= tilesPerRow * 4) return;
  const int tx = blockIdx.x % tilesPerRow, ty = blockIdx.x / tilesPerRow;
  const int tid = threadIdx.x;
  #pragma unroll
  for (int i=0;i<2;++i){
    const int e = tid + i*512;
    const int r = e >> 4, cq = (e & 15)*4;
    float4 v = *(const float4*)(src + (size_t)(ty*64 + r)*N + tx*64 + cq);
    tile[r][cq+0]=v.x; tile[r][cq+1]=v.y; tile[r][cq+2]=v.z; tile[r][cq+3]=v.w;
  }
  __syncthreads();
  #pragma unroll
  for (int i=0;i<2;++i){
    const int e = tid + i*512;
    const int orow = e >> 4, tq = (e & 15)*4;
    ushort4 o;
    o.x = f2bf(tile[tq+0][orow]); o.y = f2bf(tile[tq+1][orow]);
    o.z = f2bf(tile[tq+2][orow]); o.w = f2bf(tile[tq+3][orow]);
    *(ushort4*)(dst + (size_t)(tx*64 + orow)*256 + ty*64 + tq) = o;
  }
}

// ---------------------------------------------------------------------------
// Embedding + positional encoding + LN1(layer0): one wave per row.
// ---------------------------------------------------------------------------
__global__ __launch_bounds__(256)
void embed_ln_kernel(const int* __restrict__ idx, const float* __restrict__ emb,
                     const float* __restrict__ g, const float* __restrict__ be,
                     u16* __restrict__ x, u16* __restrict__ hb)
{
  const int tid = threadIdx.x;
  const int w = tid >> 6, l = tid & 63;
  const int row = blockIdx.x*4 + w;
  const int t = row & 255;
  const int v = idx[row];
  const int c4 = l*4;
  float4 e = *(const float4*)(emb + (size_t)v*256 + c4);
  float r[4];
  const float ef[4] = {e.x, e.y, e.z, e.w};
  #pragma unroll
  for (int i=0;i<4;++i){
    const int c = c4 + i;
    const float div = expf((float)(c & ~1) * (-9.210340371976184f/256.f));
    const float ang = (float)t * div;
    r[i] = ((c & 1) ? cosf(ang) : sinf(ang)) + ef[i];
  }
  ushort4 xo;
  xo.x = f2bf(r[0]); xo.y = f2bf(r[1]); xo.z = f2bf(r[2]); xo.w = f2bf(r[3]);
  *(ushort4*)(x + (size_t)row*256 + c4) = xo;
  float s = r[0]+r[1]+r[2]+r[3];
  float q = r[0]*r[0]+r[1]*r[1]+r[2]*r[2]+r[3]*r[3];
  #pragma unroll
  for (int m=32; m; m>>=1){ s += __shfl_xor(s,m); q += __shfl_xor(q,m); }
  const float mu = s * (1.f/256.f);
  const float var = q * (1.f/256.f) - mu*mu;
  const float rstd = rsqrtf(var + 1e-5f);
  const float4 gv = *(const float4*)(g + c4);
  const float4 bv = *(const float4*)(be + c4);
  ushort4 o;
  o.x = f2bf((r[0]-mu)*rstd*gv.x + bv.x);
  o.y = f2bf((r[1]-mu)*rstd*gv.y + bv.y);
  o.z = f2bf((r[2]-mu)*rstd*gv.z + bv.z);
  o.w = f2bf((r[3]-mu)*rstd*gv.w + bv.w);
  *(ushort4*)(hb + (size_t)row*256 + c4) = o;
}

// ---------------------------------------------------------------------------
// Plain GEMM, 2-phase dbuf staging. C[M][N] = A[M][256] @ W^T[N][256].
// 128x128 tile, 4 waves, LDS 32 KB. 1D grid (nwg = (M/128)*NY, nwg%8==0),
// bijective XCD swizzle + y-fast decode: the NY blocks sharing one A-panel
// run contiguously on one XCD -> A re-reads hit that XCD's L2.
// ---------------------------------------------------------------------------
template<int NY, bool OBF, bool RELU_, bool BIAS_>
__global__ __launch_bounds__(256)
void gemm_kernel(const u16* __restrict__ A, const u16* __restrict__ W,
                 const float* __restrict__ bias, void* __restrict__ Cv, int ldC)
{
  __shared__ __align__(16) u16 Al[2][4096];
  __shared__ __align__(16) u16 Bl[2][4096];
  const int tid = threadIdx.x;
  const int w = tid >> 6, l = tid & 63;
  const int lr = l & 15, lg = l >> 4;
  const int bid = blockIdx.x, cpx = gridDim.x >> 3;
  const int wg = (bid & 7) * cpx + (bid >> 3);
  const int m0 = (wg / NY) * 128, n0 = (wg % NY) * 128;
  const int wm = w >> 1, wn = w & 1;
  const int rowc = l >> 2;
  const int pswz = (l & 3) ^ ((l >> 3) & 3);

  f32x4 acc[4][4];
  #pragma unroll
  for (int i=0;i<4;++i)
    #pragma unroll
    for (int jn=0;jn<4;++jn) acc[i][jn] = (f32x4){0.f,0.f,0.f,0.f};

  #pragma unroll
  for (int cc=0; cc<2; ++cc){
    const int c = w + cc*4;
    gload16(A + (size_t)(m0 + 16*c + rowc)*256 + pswz*8, &Al[0][c*512]);
    gload16(W + (size_t)(n0 + 16*c + rowc)*256 + pswz*8, &Bl[0][c*512]);
  }
  __syncthreads();

  for (int kt=0; kt<8; ++kt){
    if (kt < 7){
      const int kofs = (kt+1) * 32, nb = (kt+1) & 1;
      #pragma unroll
      for (int cc=0; cc<2; ++cc){
        const int c = w + cc*4;
        gload16(A + (size_t)(m0 + 16*c + rowc)*256 + kofs + pswz*8, &Al[nb][c*512]);
        gload16(W + (size_t)(n0 + 16*c + rowc)*256 + kofs + pswz*8, &Bl[nb][c*512]);
      }
    }
    const int buf = kt & 1;
    short8 af[4], bf[4];
    #pragma unroll
    for (int mt=0; mt<4; ++mt){
      const int row = wm*64 + mt*16 + lr;
      const int kb = (lg*16) ^ ((((row>>1)&3))<<4);
      af[mt] = *(const short8*)((const char*)Al[buf] + row*64 + kb);
    }
    #pragma unroll
    for (int nt=0; nt<4; ++nt){
      const int row = wn*64 + nt*16 + lr;
      const int kb = (lg*16) ^ ((((row>>1)&3))<<4);
      bf[nt] = *(const short8*)((const char*)Bl[buf] + row*64 + kb);
    }
    #pragma unroll
    for (int mt=0; mt<4; ++mt)
      #pragma unroll
      for (int nt=0; nt<4; ++nt)
        acc[mt][nt] = __builtin_amdgcn_mfma_f32_16x16x32_bf16(af[mt], bf[nt], acc[mt][nt], 0,0,0);
    __syncthreads();
  }

  #pragma unroll
  for (int nt=0; nt<4; ++nt){
    const int col = n0 + wn*64 + nt*16 + lr;
    const float bv = BIAS_ ? bias[col] : 0.f;
    #pragma unroll
    for (int mt=0; mt<4; ++mt){
      f32x4 v = acc[mt][nt];
      #pragma unroll
      for (int r=0;r<4;++r){
        const int row = m0 + wm*64 + mt*16 + lg*4 + r;
        float val = v[r] + bv;
        if (RELU_) val = fmaxf(val, 0.f);
        if (OBF) ((u16*)Cv)[(size_t)row*ldC + col] = f2bf(val);
        else     ((float*)Cv)[(size_t)row*ldC + col] = val;
      }
    }
  }
}

// ---------------------------------------------------------------------------
// GEMM + residual + LayerNorm epilogue. Block = 64 full rows (grid 512).
// Residual stream bf16; adds in f32.
// ---------------------------------------------------------------------------
__global__ __launch_bounds__(256, 2)
void gemm_res_ln_kernel(const u16* __restrict__ A, const u16* __restrict__ W,
                        const float* __restrict__ bias,
                        const float* __restrict__ g, const float* __restrict__ be,
                        u16* __restrict__ x, u16* __restrict__ hb)
{
  __shared__ __align__(16) u16 Al[2][2048];   // [64][32]
  __shared__ __align__(16) u16 Bl[2][8192];   // [256][32]
  __shared__ float sS[64][2], sQ[64][2];
  const int tid = threadIdx.x;
  const int w = tid >> 6, l = tid & 63;
  const int lr = l & 15, lg = l >> 4;
  const int m0 = blockIdx.x * 64;
  const int wm = w >> 1, wn = w & 1;
  const int rowc = l >> 2;
  const int pswz = (l & 3) ^ ((l >> 3) & 3);

  f32x4 acc[2][2][4];
  #pragma unroll
  for (int p=0;p<2;++p)
    #pragma unroll
    for (int i=0;i<2;++i)
      #pragma unroll
      for (int jn=0;jn<4;++jn) acc[p][i][jn] = (f32x4){0.f,0.f,0.f,0.f};

  gload16(A + (size_t)(m0 + 16*w + rowc)*256 + pswz*8, &Al[0][w*512]);
  #pragma unroll
  for (int cc=0; cc<4; ++cc){
    const int c = w + cc*4;
    gload16(W + (size_t)(16*c + rowc)*256 + pswz*8, &Bl[0][c*512]);
  }
  __syncthreads();

  for (int kt=0; kt<8; ++kt){
    if (kt < 7){
      const int kofs = (kt+1)*32, nb = (kt+1)&1;
      gload16(A + (size_t)(m0 + 16*w + rowc)*256 + kofs + pswz*8, &Al[nb][w*512]);
      #pragma unroll
      for (int cc=0; cc<4; ++cc){
        const int c = w + cc*4;
        gload16(W + (size_t)(16*c + rowc)*256 + kofs + pswz*8, &Bl[nb][c*512]);
      }
    }
    const int buf = kt & 1;
    short8 af[2], bf[2][4];
    #pragma unroll
    for (int mt=0; mt<2; ++mt){
      const int row = wm*32 + mt*16 + lr;
      const int kb = (lg*16) ^ ((((row>>1)&3))<<4);
      af[mt] = *(const short8*)((const char*)Al[buf] + row*64 + kb);
    }
    #pragma unroll
    for (int p=0; p<2; ++p)
      #pragma unroll
      for (int nt=0; nt<4; ++nt){
        const int brow = p*128 + wn*64 + nt*16 + lr;
        const int kb = (lg*16) ^ ((((brow>>1)&3))<<4);
        bf[p][nt] = *(const short8*)((const char*)Bl[buf] + brow*64 + kb);
      }
    #pragma unroll
    for (int p=0; p<2; ++p)
      #pragma unroll
      for (int mt=0; mt<2; ++mt)
        #pragma unroll
        for (int nt=0; nt<4; ++nt)
          acc[p][mt][nt] = __builtin_amdgcn_mfma_f32_16x16x32_bf16(af[mt], bf[p][nt], acc[p][mt][nt], 0,0,0);
    __syncthreads();
  }

  float bcol[2][4], gcol[2][4], becol[2][4];
  #pragma unroll
  for (int p=0;p<2;++p)
    #pragma unroll
    for (int nt=0;nt<4;++nt){
      const int col = p*128 + wn*64 + nt*16 + lr;
      bcol[p][nt] = bias[col]; gcol[p][nt] = g[col]; becol[p][nt] = be[col];
    }
  float s8[2][4], q8[2][4];
  #pragma unroll
  for (int mt=0;mt<2;++mt)
    #pragma unroll
    for (int rr=0;rr<4;++rr){ s8[mt][rr]=0.f; q8[mt][rr]=0.f; }

  #pragma unroll
  for (int p=0;p<2;++p)
    #pragma unroll
    for (int mt=0;mt<2;++mt)
      #pragma unroll
      for (int nt=0;nt<4;++nt)
        #pragma unroll
        for (int rr=0;rr<4;++rr){
          const int row = m0 + wm*32 + mt*16 + lg*4 + rr;
          const int col = p*128 + wn*64 + nt*16 + lr;
          float val = acc[p][mt][nt][rr] + bcol[p][nt] + bf2f(x[(size_t)row*256 + col]);
          x[(size_t)row*256 + col] = f2bf(val);
          val = bf2f(f2bf(val));     // keep stats consistent with stored bf16
          acc[p][mt][nt][rr] = val;
          s8[mt][rr] += val; q8[mt][rr] += val*val;
        }
  #pragma unroll
  for (int mt=0;mt<2;++mt)
    #pragma unroll
    for (int rr=0;rr<4;++rr){
      #pragma unroll
      for (int m=1; m<16; m<<=1){
        s8[mt][rr] += __shfl_xor(s8[mt][rr], m);
        q8[mt][rr] += __shfl_xor(q8[mt][rr], m);
      }
      if (lr == 0){
        const int lrow = wm*32 + mt*16 + lg*4 + rr;
        sS[lrow][wn] = s8[mt][rr]; sQ[lrow][wn] = q8[mt][rr];
      }
    }
  __syncthreads();

  #pragma unroll
  for (int mt=0;mt<2;++mt)
    #pragma unroll
    for (int rr=0;rr<4;++rr){
      const int lrow = wm*32 + mt*16 + lg*4 + rr;
      const float mu = (sS[lrow][0] + sS[lrow][1]) * (1.f/256.f);
      const float var = (sQ[lrow][0] + sQ[lrow][1]) * (1.f/256.f) - mu*mu;
      const float rstd = rsqrtf(var + 1e-5f);
      #pragma unroll
      for (int p=0;p<2;++p)
        #pragma unroll
        for (int nt=0;nt<4;++nt){
          const int col = p*128 + wn*64 + nt*16 + lr;
          const float out = (acc[p][mt][nt][rr] - mu)*rstd*gcol[p][nt] + becol[p][nt];
          hb[(size_t)(m0+lrow)*256 + col] = f2bf(out);
        }
    }
}

// ---------------------------------------------------------------------------
// Fused causal attention, split into 2 half-blocks per (b,h): grid (512, 2).
// Half 0 owns q-tiles 0-7 (stages only t<128 of K/V); half 1 owns 8-15
// (full staging). Each wave computes ONE q-row-tile rt = half*8 + w.
// SWAPPED QK^T (q = lane column) => in-lane softmax; PV A-frag via bf16x2
// pack + 4-lane-group shfl (no P-LDS). LDS 32 KiB.
// ---------------------------------------------------------------------------
__global__ __launch_bounds__(512, 6)
void attn_kernel(const u16* __restrict__ qkv, u16* __restrict__ att)
{
  __shared__ __align__(16) u16 sK[16384];   // [256 t][64 d] swz (row 128B)
  __shared__ __align__(16) u16 sV[16384];   // [64 hd][256 t] swz (row 512B)
  const int bh = blockIdx.x, half = blockIdx.y;
  const int b = bh >> 2, h = bh & 3;
  const int tid = threadIdx.x;
  const int w = tid >> 6, l = tid & 63, lr = l & 15, lg = l >> 4;
  const u16* base = qkv + (size_t)(b*256)*768;

  // stage K rows t < 128*(1+half)
  const int nKit = 2 + 2*half;
  #pragma unroll
  for (int it=0; it<4; ++it){
    if (it < nKit){
      const int c = tid + it*512;
      const int t = c >> 3, p = c & 7;
      uint4 val = *(const uint4*)(base + (size_t)t*768 + 256 + h*64 + p*8);
      *(uint4*)((char*)sK + t*128 + ((p*16) ^ ((t&7)<<4))) = val;
    }
  }
  // stage V cols t < 128*(1+half)
  const int nVit = 4 + 4*half;
  #pragma unroll
  for (int it=0; it<8; ++it){
    if (it < nVit){
      const int c = tid + it*512;
      const int t = c >> 4, hdq = c & 15;
      ushort4 v = *(const ushort4*)(base + (size_t)t*768 + 512 + h*64 + hdq*4);
      #pragma unroll
      for (int j=0;j<4;++j){
        const int hd = hdq*4 + j;
        *(u16*)((char*)sV + hd*512 + ((t*2) ^ ((hd&31)<<4))) = ((const u16*)&v)[j];
      }
    }
  }
  __syncthreads();

  u16* ab = att + (size_t)(b*256)*256 + h*64;
  const float c1 = 0.09016844005556021f;   // (1/16) * log2(e)
  const int srcA = lr + (lg & 1)*32;
  const int srcB = srcA + 16;
  const bool selB = (lg >> 1) != 0;

  const int rt = half*8 + w;               // this wave's q-row-tile
  const u16* qp = base + (size_t)(rt*16 + lr)*768 + h*64;
  const short8 qf0 = *(const short8*)(qp + lg*8);
  const short8 qf1 = *(const short8*)(qp + 32 + lg*8);

  f32x4 acc[16];
  #pragma unroll
  for (int nt=0; nt<16; ++nt) acc[nt] = (f32x4){0.f,0.f,0.f,0.f};
  #pragma unroll
  for (int nt=0; nt<16; ++nt){
    if (nt <= rt){
      const int row = nt*16 + lr;
      const int swz = (row & 7) << 4;
      short8 k0 = *(const short8*)((const char*)sK + row*128 + ((lg*16) ^ swz));
      short8 k1 = *(const short8*)((const char*)sK + row*128 + ((64 + lg*16) ^ swz));
      acc[nt] = __builtin_amdgcn_mfma_f32_16x16x32_bf16(k0, qf0, acc[nt], 0,0,0);
      acc[nt] = __builtin_amdgcn_mfma_f32_16x16x32_bf16(k1, qf1, acc[nt], 0,0,0);
    }
  }
  #pragma unroll
  for (int nt=0; nt<16; ++nt){
    if (nt == rt){
      #pragma unroll
      for (int r=0;r<4;++r)
        acc[nt][r] = (lg*4 + r > lr) ? -3.0e38f : acc[nt][r];
    }
  }

  float m_ = -3.0e38f;
  #pragma unroll
  for (int nt=0; nt<16; ++nt){
    if (nt <= rt){
      float t01 = fmaxf(acc[nt][0], acc[nt][1]);
      float t23 = fmaxf(acc[nt][2], acc[nt][3]);
      m_ = fmaxf(m_, fmaxf(t01, t23));
    }
  }
  m_ = fmaxf(m_, __shfl_xor(m_, 16));
  m_ = fmaxf(m_, __shfl_xor(m_, 32));
  const float mm = m_ * c1;
  float s_ = 0.f;
  #pragma unroll
  for (int nt=0; nt<16; ++nt){
    if (nt <= rt){
      #pragma unroll
      for (int r=0;r<4;++r){
        const float p = exp2f(fmaf(acc[nt][r], c1, -mm));
        acc[nt][r] = p;
        s_ += p;
      }
    }
  }
  s_ += __shfl_xor(s_, 16);
  s_ += __shfl_xor(s_, 32);
  const float inv = 1.f / s_;

  f32x4 oacc[4];
  #pragma unroll
  for (int nt=0; nt<4; ++nt) oacc[nt] = (f32x4){0.f,0.f,0.f,0.f};
  #pragma unroll
  for (int tc=0; tc<8; ++tc){
    if (tc <= (rt >> 1)){
      const int nt0 = 2*tc, nt1 = 2*tc+1;
      const float p00 = acc[nt0][0]*inv, p01 = acc[nt0][1]*inv;
      const float p02 = acc[nt0][2]*inv, p03 = acc[nt0][3]*inv;
      const float p10 = (nt1 <= rt) ? acc[nt1][0]*inv : 0.f;
      const float p11 = (nt1 <= rt) ? acc[nt1][1]*inv : 0.f;
      const float p12 = (nt1 <= rt) ? acc[nt1][2]*inv : 0.f;
      const float p13 = (nt1 <= rt) ? acc[nt1][3]*inv : 0.f;
      const u32 A0 = pk2(p00,p01), A1 = pk2(p02,p03);
      const u32 B0 = pk2(p10,p11), B1 = pk2(p12,p13);
      const u32 a0A = __shfl((int)A0, srcA), a0B = __shfl((int)B0, srcA);
      const u32 a1A = __shfl((int)A1, srcA), a1B = __shfl((int)B1, srcA);
      const u32 a2A = __shfl((int)A0, srcB), a2B = __shfl((int)B0, srcB);
      const u32 a3A = __shfl((int)A1, srcB), a3B = __shfl((int)B1, srcB);
      union { u32 u[4]; short8 s; } apu;
      apu.u[0] = selB ? a0B : a0A;
      apu.u[1] = selB ? a1B : a1A;
      apu.u[2] = selB ? a2B : a2A;
      apu.u[3] = selB ? a3B : a3A;
      const short8 ap = apu.s;
      #pragma unroll
      for (int nt=0; nt<4; ++nt){
        const int vrow = nt*16 + lr;
        const short8 bv = *(const short8*)((const char*)sV + vrow*512 +
                             ((tc*64 + lg*16) ^ ((vrow&31)<<4)));
        oacc[nt] = __builtin_amdgcn_mfma_f32_16x16x32_bf16(ap, bv, oacc[nt], 0,0,0);
      }
    }
  }

  #pragma unroll
  for (int nt=0; nt<4; ++nt)
    #pragma unroll
    for (int r=0;r<4;++r){
      const int row = rt*16 + lg*4 + r;
      ab[(size_t)row*256 + nt*16 + lr] = f2bf(oacc[nt][r]);
    }
}

// ---------------------------------------------------------------------------
extern "C" void kernel_launch(void* const* d_in, const int* in_sizes, int n_in,
                              void* d_out, int out_size, void* d_ws, size_t ws_size,
                              hipStream_t stream)
{
  (void)in_sizes; (void)n_in; (void)out_size; (void)ws_size;
  const int*   idx = (const int*)  d_in[0];
  const float* tok = (const float*)d_in[1];
  const float* Wq  = (const float*)d_in[2];
  const float* Wk  = (const float*)d_in[3];
  const float* Wv  = (const float*)d_in[4];
  const float* Wo  = (const float*)d_in[5];
  const float* bo  = (const float*)d_in[6];
  const float* W1  = (const float*)d_in[7];
  const float* b1  = (const float*)d_in[8];
  const float* W2  = (const float*)d_in[9];
  const float* b2  = (const float*)d_in[10];
  const float* g1  = (const float*)d_in[11];
  const float* be1 = (const float*)d_in[12];
  const float* g2  = (const float*)d_in[13];
  const float* be2 = (const float*)d_in[14];
  const float* gf  = (const float*)d_in[15];
  const float* bfi = (const float*)d_in[16];
  const float* Wh  = (const float*)d_in[17];
  const float* bh  = (const float*)d_in[18];

  char* ws = (char*)d_ws;
  u16*   x    = (u16*)ws;    ws += (size_t)32768*256*2;   // residual stream bf16
  u16*   hb   = (u16*)ws;    ws += (size_t)32768*256*2;   // LN output bf16
  u16*   mid  = (u16*)ws;    ws += (size_t)32768*256*2;   // FFN mid bf16
  u16*   qkv  = (u16*)ws;    ws += (size_t)32768*768*2;
  u16*   att  = (u16*)ws;    ws += (size_t)32768*256*2;   // attn out bf16
  u16*   WqkvT= (u16*)ws;    ws += (size_t)8*768*256*2;
  u16*   WoT  = (u16*)ws;    ws += (size_t)8*256*256*2;
  u16*   W1T  = (u16*)ws;    ws += (size_t)8*256*256*2;
  u16*   W2T  = (u16*)ws;    ws += (size_t)8*256*256*2;
  u16*   WhT  = (u16*)ws;    ws += (size_t)512*256*2;

  wconv_kernel<<<dim3(32,49),512,0,stream>>>(Wq,Wk,Wv,Wo,W1,W2,Wh,WqkvT,WoT,W1T,W2T,WhT);
  embed_ln_kernel<<<8192,256,0,stream>>>(idx, tok, g1, be1, x, hb);
  for (int l=0; l<8; ++l){
    gemm_kernel<6,true,false,false><<<1536,256,0,stream>>>(
        hb, WqkvT + (size_t)l*196608, nullptr, qkv, 768);
    attn_kernel<<<dim3(512,2),512,0,stream>>>(qkv, att);
    gemm_res_ln_kernel<<<512,256,0,stream>>>(
        att, WoT + (size_t)l*65536, bo + l*256, g2 + l*256, be2 + l*256, x, hb);
    gemm_kernel<2,true,true,true><<<512,256,0,stream>>>(
        hb, W1T + (size_t)l*65536, b1 + l*256, mid, 256);
    const float* gn = (l < 7) ? (g1 + (l+1)*256) : gf;
    const float* bn = (l < 7) ? (be1 + (l+1)*256) : bfi;
    gemm_res_ln_kernel<<<512,256,0,stream>>>(
        mid, W2T + (size_t)l*65536, b2 + l*256, gn, bn, x, hb);
  }
  gemm_kernel<4,false,false,true><<<1024,256,0,stream>>>(
      hb, WhT, bh, (float*)d_out, 512);
}

// Round 14
// 795.897 us; speedup vs baseline: 1.0730x; 1.0073x over previous
//
#include <hip/hip_runtime.h>
#include <hip/hip_bf16.h>

typedef unsigned short u16;
typedef unsigned int u32;
typedef __attribute__((ext_vector_type(8))) short short8;   // 8 bf16 (4 VGPRs)
typedef __attribute__((ext_vector_type(4))) float f32x4;    // MFMA accumulator

#define DEV static __device__ __forceinline__

DEV u16 f2bf(float x){
  union { __hip_bfloat16 b; u16 u; } c;
  c.b = __float2bfloat16(x);   // RNE
  return c.u;
}
DEV float bf2f(u16 u){
  union { float f; unsigned i; } c;
  c.i = ((unsigned)u) << 16;
  return c.f;
}
DEV u32 pk2(float lo, float hi){          // bf16x2: low half = lo
  return ((u32)f2bf(hi) << 16) | (u32)f2bf(lo);
}

DEV void gload16(const void* g, void* lds){
  __builtin_amdgcn_global_load_lds((const __attribute__((address_space(1))) void*)g,
                                   (__attribute__((address_space(3))) void*)lds, 16, 0, 0);
}

// ---------------------------------------------------------------------------
// Weight convert + transpose: src fp32 [K=256][N] -> dst bf16 [N][256]
// ---------------------------------------------------------------------------
__global__ __launch_bounds__(512)
void wconv_kernel(const float* __restrict__ Wq, const float* __restrict__ Wk,
                  const float* __restrict__ Wv, const float* __restrict__ Wo,
                  const float* __restrict__ W1, const float* __restrict__ W2,
                  const float* __restrict__ Wh,
                  u16* __restrict__ WqkvT, u16* __restrict__ WoT,
                  u16* __restrict__ W1T, u16* __restrict__ W2T, u16* __restrict__ WhT)
{
  __shared__ float tile[64][65];
  const int j = blockIdx.y;
  int N = 256;
  const float* src; u16* dst;
  if (j < 48){
    const int li = j / 6, t = j % 6;
    switch(t){
      case 0:  src = Wq + li*65536; dst = WqkvT + li*196608;          break;
      case 1:  src = Wk + li*65536; dst = WqkvT + li*196608 + 65536;  break;
      case 2:  src = Wv + li*65536; dst = WqkvT + li*196608 + 131072; break;
      case 3:  src = Wo + li*65536; dst = WoT  + li*65536;            break;
      case 4:  src = W1 + li*65536; dst = W1T  + li*65536;            break;
      default: src = W2 + li*65536; dst = W2T  + li*65536;            break;
    }
  } else { N = 512; src = Wh; dst = WhT; }
  const int tilesPerRow = N >> 6;
  if ((int)blockIdx.x >= tilesPerRow * 4) return;
  const int tx = blockIdx.x % tilesPerRow, ty = blockIdx.x / tilesPerRow;
  const int tid = threadIdx.x;
  #pragma unroll
  for (int i=0;i<2;++i){
    const int e = tid + i*512;
    const int r = e >> 4, cq = (e & 15)*4;
    float4 v = *(const float4*)(src + (size_t)(ty*64 + r)*N + tx*64 + cq);
    tile[r][cq+0]=v.x; tile[r][cq+1]=v.y; tile[r][cq+2]=v.z; tile[r][cq+3]=v.w;
  }
  __syncthreads();
  #pragma unroll
  for (int i=0;i<2;++i){
    const int e = tid + i*512;
    const int orow = e >> 4, tq = (e & 15)*4;
    ushort4 o;
    o.x = f2bf(tile[tq+0][orow]); o.y = f2bf(tile[tq+1][orow]);
    o.z = f2bf(tile[tq+2][orow]); o.w = f2bf(tile[tq+3][orow]);
    *(ushort4*)(dst + (size_t)(tx*64 + orow)*256 + ty*64 + tq) = o;
  }
}

// ---------------------------------------------------------------------------
// Embedding + positional encoding + LN1(layer0): one wave per row.
// ---------------------------------------------------------------------------
__global__ __launch_bounds__(256)
void embed_ln_kernel(const int* __restrict__ idx, const float* __restrict__ emb,
                     const float* __restrict__ g, const float* __restrict__ be,
                     u16* __restrict__ x, u16* __restrict__ hb)
{
  const int tid = threadIdx.x;
  const int w = tid >> 6, l = tid & 63;
  const int row = blockIdx.x*4 + w;
  const int t = row & 255;
  const int v = idx[row];
  const int c4 = l*4;
  float4 e = *(const float4*)(emb + (size_t)v*256 + c4);
  float r[4];
  const float ef[4] = {e.x, e.y, e.z, e.w};
  #pragma unroll
  for (int i=0;i<4;++i){
    const int c = c4 + i;
    const float div = expf((float)(c & ~1) * (-9.210340371976184f/256.f));
    const float ang = (float)t * div;
    r[i] = ((c & 1) ? cosf(ang) : sinf(ang)) + ef[i];
  }
  ushort4 xo;
  xo.x = f2bf(r[0]); xo.y = f2bf(r[1]); xo.z = f2bf(r[2]); xo.w = f2bf(r[3]);
  *(ushort4*)(x + (size_t)row*256 + c4) = xo;
  float s = r[0]+r[1]+r[2]+r[3];
  float q = r[0]*r[0]+r[1]*r[1]+r[2]*r[2]+r[3]*r[3];
  #pragma unroll
  for (int m=32; m; m>>=1){ s += __shfl_xor(s,m); q += __shfl_xor(q,m); }
  const float mu = s * (1.f/256.f);
  const float var = q * (1.f/256.f) - mu*mu;
  const float rstd = rsqrtf(var + 1e-5f);
  const float4 gv = *(const float4*)(g + c4);
  const float4 bv = *(const float4*)(be + c4);
  ushort4 o;
  o.x = f2bf((r[0]-mu)*rstd*gv.x + bv.x);
  o.y = f2bf((r[1]-mu)*rstd*gv.y + bv.y);
  o.z = f2bf((r[2]-mu)*rstd*gv.z + bv.z);
  o.w = f2bf((r[3]-mu)*rstd*gv.w + bv.w);
  *(ushort4*)(hb + (size_t)row*256 + c4) = o;
}

// ---------------------------------------------------------------------------
// Plain GEMM, 2-phase dbuf staging. C[M][N] = A[M][256] @ W^T[N][256].
// 128x128 tile, 4 waves, LDS 32 KB.
// ---------------------------------------------------------------------------
template<bool OBF, bool RELU_, bool BIAS_>
__global__ __launch_bounds__(256)
void gemm_kernel(const u16* __restrict__ A, const u16* __restrict__ W,
                 const float* __restrict__ bias, void* __restrict__ Cv, int ldC)
{
  __shared__ __align__(16) u16 Al[2][4096];
  __shared__ __align__(16) u16 Bl[2][4096];
  const int tid = threadIdx.x;
  const int w = tid >> 6, l = tid & 63;
  const int lr = l & 15, lg = l >> 4;
  const int m0 = blockIdx.x * 128, n0 = blockIdx.y * 128;
  const int wm = w >> 1, wn = w & 1;
  const int rowc = l >> 2;
  const int pswz = (l & 3) ^ ((l >> 3) & 3);

  f32x4 acc[4][4];
  #pragma unroll
  for (int i=0;i<4;++i)
    #pragma unroll
    for (int jn=0;jn<4;++jn) acc[i][jn] = (f32x4){0.f,0.f,0.f,0.f};

  #pragma unroll
  for (int cc=0; cc<2; ++cc){
    const int c = w + cc*4;
    gload16(A + (size_t)(m0 + 16*c + rowc)*256 + pswz*8, &Al[0][c*512]);
    gload16(W + (size_t)(n0 + 16*c + rowc)*256 + pswz*8, &Bl[0][c*512]);
  }
  __syncthreads();

  for (int kt=0; kt<8; ++kt){
    if (kt < 7){
      const int kofs = (kt+1) * 32, nb = (kt+1) & 1;
      #pragma unroll
      for (int cc=0; cc<2; ++cc){
        const int c = w + cc*4;
        gload16(A + (size_t)(m0 + 16*c + rowc)*256 + kofs + pswz*8, &Al[nb][c*512]);
        gload16(W + (size_t)(n0 + 16*c + rowc)*256 + kofs + pswz*8, &Bl[nb][c*512]);
      }
    }
    const int buf = kt & 1;
    short8 af[4], bf[4];
    #pragma unroll
    for (int mt=0; mt<4; ++mt){
      const int row = wm*64 + mt*16 + lr;
      const int kb = (lg*16) ^ ((((row>>1)&3))<<4);
      af[mt] = *(const short8*)((const char*)Al[buf] + row*64 + kb);
    }
    #pragma unroll
    for (int nt=0; nt<4; ++nt){
      const int row = wn*64 + nt*16 + lr;
      const int kb = (lg*16) ^ ((((row>>1)&3))<<4);
      bf[nt] = *(const short8*)((const char*)Bl[buf] + row*64 + kb);
    }
    #pragma unroll
    for (int mt=0; mt<4; ++mt)
      #pragma unroll
      for (int nt=0; nt<4; ++nt)
        acc[mt][nt] = __builtin_amdgcn_mfma_f32_16x16x32_bf16(af[mt], bf[nt], acc[mt][nt], 0,0,0);
    __syncthreads();
  }

  #pragma unroll
  for (int nt=0; nt<4; ++nt){
    const int col = n0 + wn*64 + nt*16 + lr;
    const float bv = BIAS_ ? bias[col] : 0.f;
    #pragma unroll
    for (int mt=0; mt<4; ++mt){
      f32x4 v = acc[mt][nt];
      #pragma unroll
      for (int r=0;r<4;++r){
        const int row = m0 + wm*64 + mt*16 + lg*4 + r;
        float val = v[r] + bv;
        if (RELU_) val = fmaxf(val, 0.f);
        if (OBF) ((u16*)Cv)[(size_t)row*ldC + col] = f2bf(val);
        else     ((float*)Cv)[(size_t)row*ldC + col] = val;
      }
    }
  }
}

// ---------------------------------------------------------------------------
// GEMM + residual + LayerNorm epilogue. Block = 64 full rows (grid 512).
// Residual stream bf16; adds in f32.
// ---------------------------------------------------------------------------
__global__ __launch_bounds__(256, 2)
void gemm_res_ln_kernel(const u16* __restrict__ A, const u16* __restrict__ W,
                        const float* __restrict__ bias,
                        const float* __restrict__ g, const float* __restrict__ be,
                        u16* __restrict__ x, u16* __restrict__ hb)
{
  __shared__ __align__(16) u16 Al[2][2048];   // [64][32]
  __shared__ __align__(16) u16 Bl[2][8192];   // [256][32]
  __shared__ float sS[64][2], sQ[64][2];
  const int tid = threadIdx.x;
  const int w = tid >> 6, l = tid & 63;
  const int lr = l & 15, lg = l >> 4;
  const int m0 = blockIdx.x * 64;
  const int wm = w >> 1, wn = w & 1;
  const int rowc = l >> 2;
  const int pswz = (l & 3) ^ ((l >> 3) & 3);

  f32x4 acc[2][2][4];
  #pragma unroll
  for (int p=0;p<2;++p)
    #pragma unroll
    for (int i=0;i<2;++i)
      #pragma unroll
      for (int jn=0;jn<4;++jn) acc[p][i][jn] = (f32x4){0.f,0.f,0.f,0.f};

  gload16(A + (size_t)(m0 + 16*w + rowc)*256 + pswz*8, &Al[0][w*512]);
  #pragma unroll
  for (int cc=0; cc<4; ++cc){
    const int c = w + cc*4;
    gload16(W + (size_t)(16*c + rowc)*256 + pswz*8, &Bl[0][c*512]);
  }
  __syncthreads();

  for (int kt=0; kt<8; ++kt){
    if (kt < 7){
      const int kofs = (kt+1)*32, nb = (kt+1)&1;
      gload16(A + (size_t)(m0 + 16*w + rowc)*256 + kofs + pswz*8, &Al[nb][w*512]);
      #pragma unroll
      for (int cc=0; cc<4; ++cc){
        const int c = w + cc*4;
        gload16(W + (size_t)(16*c + rowc)*256 + kofs + pswz*8, &Bl[nb][c*512]);
      }
    }
    const int buf = kt & 1;
    short8 af[2], bf[2][4];
    #pragma unroll
    for (int mt=0; mt<2; ++mt){
      const int row = wm*32 + mt*16 + lr;
      const int kb = (lg*16) ^ ((((row>>1)&3))<<4);
      af[mt] = *(const short8*)((const char*)Al[buf] + row*64 + kb);
    }
    #pragma unroll
    for (int p=0; p<2; ++p)
      #pragma unroll
      for (int nt=0; nt<4; ++nt){
        const int brow = p*128 + wn*64 + nt*16 + lr;
        const int kb = (lg*16) ^ ((((brow>>1)&3))<<4);
        bf[p][nt] = *(const short8*)((const char*)Bl[buf] + brow*64 + kb);
      }
    #pragma unroll
    for (int p=0; p<2; ++p)
      #pragma unroll
      for (int mt=0; mt<2; ++mt)
        #pragma unroll
        for (int nt=0; nt<4; ++nt)
          acc[p][mt][nt] = __builtin_amdgcn_mfma_f32_16x16x32_bf16(af[mt], bf[p][nt], acc[p][mt][nt], 0,0,0);
    __syncthreads();
  }

  float bcol[2][4], gcol[2][4], becol[2][4];
  #pragma unroll
  for (int p=0;p<2;++p)
    #pragma unroll
    for (int nt=0;nt<4;++nt){
      const int col = p*128 + wn*64 + nt*16 + lr;
      bcol[p][nt] = bias[col]; gcol[p][nt] = g[col]; becol[p][nt] = be[col];
    }
  float s8[2][4], q8[2][4];
  #pragma unroll
  for (int mt=0;mt<2;++mt)
    #pragma unroll
    for (int rr=0;rr<4;++rr){ s8[mt][rr]=0.f; q8[mt][rr]=0.f; }

  #pragma unroll
  for (int p=0;p<2;++p)
    #pragma unroll
    for (int mt=0;mt<2;++mt)
      #pragma unroll
      for (int nt=0;nt<4;++nt)
        #pragma unroll
        for (int rr=0;rr<4;++rr){
          const int row = m0 + wm*32 + mt*16 + lg*4 + rr;
          const int col = p*128 + wn*64 + nt*16 + lr;
          float val = acc[p][mt][nt][rr] + bcol[p][nt] + bf2f(x[(size_t)row*256 + col]);
          x[(size_t)row*256 + col] = f2bf(val);
          val = bf2f(f2bf(val));     // keep stats consistent with stored bf16
          acc[p][mt][nt][rr] = val;
          s8[mt][rr] += val; q8[mt][rr] += val*val;
        }
  #pragma unroll
  for (int mt=0;mt<2;++mt)
    #pragma unroll
    for (int rr=0;rr<4;++rr){
      #pragma unroll
      for (int m=1; m<16; m<<=1){
        s8[mt][rr] += __shfl_xor(s8[mt][rr], m);
        q8[mt][rr] += __shfl_xor(q8[mt][rr], m);
      }
      if (lr == 0){
        const int lrow = wm*32 + mt*16 + lg*4 + rr;
        sS[lrow][wn] = s8[mt][rr]; sQ[lrow][wn] = q8[mt][rr];
      }
    }
  __syncthreads();

  #pragma unroll
  for (int mt=0;mt<2;++mt)
    #pragma unroll
    for (int rr=0;rr<4;++rr){
      const int lrow = wm*32 + mt*16 + lg*4 + rr;
      const float mu = (sS[lrow][0] + sS[lrow][1]) * (1.f/256.f);
      const float var = (sQ[lrow][0] + sQ[lrow][1]) * (1.f/256.f) - mu*mu;
      const float rstd = rsqrtf(var + 1e-5f);
      #pragma unroll
      for (int p=0;p<2;++p)
        #pragma unroll
        for (int nt=0;nt<4;++nt){
          const int col = p*128 + wn*64 + nt*16 + lr;
          const float out = (acc[p][mt][nt][rr] - mu)*rstd*gcol[p][nt] + becol[p][nt];
          hb[(size_t)(m0+lrow)*256 + col] = f2bf(out);
        }
    }
}

// ---------------------------------------------------------------------------
// Fused causal attention, one block per (b,h): 8 waves x 512 threads.
// SWAPPED QK^T (S^T tile, q = lane column) => in-lane softmax.
// PV A-fragment built in-register via bf16x2 pack + 4-lane-group shfl.
// ---------------------------------------------------------------------------
__global__ __launch_bounds__(512, 4)
void attn_kernel(const u16* __restrict__ qkv, u16* __restrict__ att)
{
  __shared__ __align__(16) u16 sK[16384];   // [256 t][64 d] swz (row 128B)
  __shared__ __align__(16) u16 sV[16384];   // [64 hd][256 t] swz (row 512B)
  const int bh = blockIdx.x;
  const int b = bh >> 2, h = bh & 3;
  const int tid = threadIdx.x;
  const int w = tid >> 6, l = tid & 63, lr = l & 15, lg = l >> 4;
  const u16* base = qkv + (size_t)(b*256)*768;

  #pragma unroll
  for (int it=0; it<4; ++it){
    const int c = tid + it*512;
    const int t = c >> 3, p = c & 7;
    uint4 val = *(const uint4*)(base + (size_t)t*768 + 256 + h*64 + p*8);
    *(uint4*)((char*)sK + t*128 + ((p*16) ^ ((t&7)<<4))) = val;
  }
  #pragma unroll
  for (int it=0; it<8; ++it){
    const int c = tid + it*512;
    const int t = c >> 4, hdq = c & 15;
    ushort4 v = *(const ushort4*)(base + (size_t)t*768 + 512 + h*64 + hdq*4);
    #pragma unroll
    for (int j=0;j<4;++j){
      const int hd = hdq*4 + j;
      *(u16*)((char*)sV + hd*512 + ((t*2) ^ ((hd&31)<<4))) = ((const u16*)&v)[j];
    }
  }
  __syncthreads();

  u16* ab = att + (size_t)(b*256)*256 + h*64;
  const float c1 = 0.09016844005556021f;   // (1/16) * log2(e)
  const int srcA = lr + (lg & 1)*32;
  const int srcB = srcA + 16;
  const bool selB = (lg >> 1) != 0;

  #pragma unroll
  for (int ph=0; ph<2; ++ph){
    const int rt = ph ? (15 - w) : w;
    const u16* qp = base + (size_t)(rt*16 + lr)*768 + h*64;
    const short8 qf0 = *(const short8*)(qp + lg*8);
    const short8 qf1 = *(const short8*)(qp + 32 + lg*8);

    f32x4 acc[16];
    #pragma unroll
    for (int nt=0; nt<16; ++nt) acc[nt] = (f32x4){0.f,0.f,0.f,0.f};
    #pragma unroll
    for (int nt=0; nt<16; ++nt){
      if (nt <= rt){
        const int row = nt*16 + lr;
        const int swz = (row & 7) << 4;
        short8 k0 = *(const short8*)((const char*)sK + row*128 + ((lg*16) ^ swz));
        short8 k1 = *(const short8*)((const char*)sK + row*128 + ((64 + lg*16) ^ swz));
        acc[nt] = __builtin_amdgcn_mfma_f32_16x16x32_bf16(k0, qf0, acc[nt], 0,0,0);
        acc[nt] = __builtin_amdgcn_mfma_f32_16x16x32_bf16(k1, qf1, acc[nt], 0,0,0);
      }
    }
    #pragma unroll
    for (int nt=0; nt<16; ++nt){
      if (nt == rt){
        #pragma unroll
        for (int r=0;r<4;++r)
          acc[nt][r] = (lg*4 + r > lr) ? -3.0e38f : acc[nt][r];
      }
    }

    float m_ = -3.0e38f;
    #pragma unroll
    for (int nt=0; nt<16; ++nt){
      if (nt <= rt){
        float t01 = fmaxf(acc[nt][0], acc[nt][1]);
        float t23 = fmaxf(acc[nt][2], acc[nt][3]);
        m_ = fmaxf(m_, fmaxf(t01, t23));
      }
    }
    m_ = fmaxf(m_, __shfl_xor(m_, 16));
    m_ = fmaxf(m_, __shfl_xor(m_, 32));
    const float mm = m_ * c1;
    float s_ = 0.f;
    #pragma unroll
    for (int nt=0; nt<16; ++nt){
      if (nt <= rt){
        #pragma unroll
        for (int r=0;r<4;++r){
          const float p = exp2f(fmaf(acc[nt][r], c1, -mm));
          acc[nt][r] = p;
          s_ += p;
        }
      }
    }
    s_ += __shfl_xor(s_, 16);
    s_ += __shfl_xor(s_, 32);
    const float inv = 1.f / s_;

    f32x4 oacc[4];
    #pragma unroll
    for (int nt=0; nt<4; ++nt) oacc[nt] = (f32x4){0.f,0.f,0.f,0.f};
    #pragma unroll
    for (int tc=0; tc<8; ++tc){
      if (tc <= (rt >> 1)){
        const int nt0 = 2*tc, nt1 = 2*tc+1;
        const float p00 = acc[nt0][0]*inv, p01 = acc[nt0][1]*inv;
        const float p02 = acc[nt0][2]*inv, p03 = acc[nt0][3]*inv;
        const float p10 = (nt1 <= rt) ? acc[nt1][0]*inv : 0.f;
        const float p11 = (nt1 <= rt) ? acc[nt1][1]*inv : 0.f;
        const float p12 = (nt1 <= rt) ? acc[nt1][2]*inv : 0.f;
        const float p13 = (nt1 <= rt) ? acc[nt1][3]*inv : 0.f;
        const u32 A0 = pk2(p00,p01), A1 = pk2(p02,p03);
        const u32 B0 = pk2(p10,p11), B1 = pk2(p12,p13);
        const u32 a0A = __shfl((int)A0, srcA), a0B = __shfl((int)B0, srcA);
        const u32 a1A = __shfl((int)A1, srcA), a1B = __shfl((int)B1, srcA);
        const u32 a2A = __shfl((int)A0, srcB), a2B = __shfl((int)B0, srcB);
        const u32 a3A = __shfl((int)A1, srcB), a3B = __shfl((int)B1, srcB);
        union { u32 u[4]; short8 s; } apu;
        apu.u[0] = selB ? a0B : a0A;
        apu.u[1] = selB ? a1B : a1A;
        apu.u[2] = selB ? a2B : a2A;
        apu.u[3] = selB ? a3B : a3A;
        const short8 ap = apu.s;
        #pragma unroll
        for (int nt=0; nt<4; ++nt){
          const int vrow = nt*16 + lr;
          const short8 bv = *(const short8*)((const char*)sV + vrow*512 +
                               ((tc*64 + lg*16) ^ ((vrow&31)<<4)));
          oacc[nt] = __builtin_amdgcn_mfma_f32_16x16x32_bf16(ap, bv, oacc[nt], 0,0,0);
        }
      }
    }

    #pragma unroll
    for (int nt=0; nt<4; ++nt)
      #pragma unroll
      for (int r=0;r<4;++r){
        const int row = rt*16 + lg*4 + r;
        ab[(size_t)row*256 + nt*16 + lr] = f2bf(oacc[nt][r]);
      }
  }
}

// ---------------------------------------------------------------------------
extern "C" void kernel_launch(void* const* d_in, const int* in_sizes, int n_in,
                              void* d_out, int out_size, void* d_ws, size_t ws_size,
                              hipStream_t stream)
{
  (void)in_sizes; (void)n_in; (void)out_size; (void)ws_size;
  const int*   idx = (const int*)  d_in[0];
  const float* tok = (const float*)d_in[1];
  const float* Wq  = (const float*)d_in[2];
  const float* Wk  = (const float*)d_in[3];
  const float* Wv  = (const float*)d_in[4];
  const float* Wo  = (const float*)d_in[5];
  const float* bo  = (const float*)d_in[6];
  const float* W1  = (const float*)d_in[7];
  const float* b1  = (const float*)d_in[8];
  const float* W2  = (const float*)d_in[9];
  const float* b2  = (const float*)d_in[10];
  const float* g1  = (const float*)d_in[11];
  const float* be1 = (const float*)d_in[12];
  const float* g2  = (const float*)d_in[13];
  const float* be2 = (const float*)d_in[14];
  const float* gf  = (const float*)d_in[15];
  const float* bfi = (const float*)d_in[16];
  const float* Wh  = (const float*)d_in[17];
  const float* bh  = (const float*)d_in[18];

  char* ws = (char*)d_ws;
  u16*   x    = (u16*)ws;    ws += (size_t)32768*256*2;   // residual stream bf16
  u16*   hb   = (u16*)ws;    ws += (size_t)32768*256*2;   // LN output bf16
  u16*   mid  = (u16*)ws;    ws += (size_t)32768*256*2;   // FFN mid bf16
  u16*   qkv  = (u16*)ws;    ws += (size_t)32768*768*2;
  u16*   att  = (u16*)ws;    ws += (size_t)32768*256*2;   // attn out bf16
  u16*   WqkvT= (u16*)ws;    ws += (size_t)8*768*256*2;
  u16*   WoT  = (u16*)ws;    ws += (size_t)8*256*256*2;
  u16*   W1T  = (u16*)ws;    ws += (size_t)8*256*256*2;
  u16*   W2T  = (u16*)ws;    ws += (size_t)8*256*256*2;
  u16*   WhT  = (u16*)ws;    ws += (size_t)512*256*2;

  wconv_kernel<<<dim3(32,49),512,0,stream>>>(Wq,Wk,Wv,Wo,W1,W2,Wh,WqkvT,WoT,W1T,W2T,WhT);
  embed_ln_kernel<<<8192,256,0,stream>>>(idx, tok, g1, be1, x, hb);
  for (int l=0; l<8; ++l){
    gemm_kernel<true,false,false><<<dim3(256,6),256,0,stream>>>(
        hb, WqkvT + (size_t)l*196608, nullptr, qkv, 768);
    attn_kernel<<<512,512,0,stream>>>(qkv, att);
    gemm_res_ln_kernel<<<512,256,0,stream>>>(
        att, WoT + (size_t)l*65536, bo + l*256, g2 + l*256, be2 + l*256, x, hb);
    gemm_kernel<true,true,true><<<dim3(256,2),256,0,stream>>>(
        hb, W1T + (size_t)l*65536, b1 + l*256, mid, 256);
    const float* gn = (l < 7) ? (g1 + (l+1)*256) : gf;
    const float* bn = (l < 7) ? (be1 + (l+1)*256) : bfi;
    gemm_res_ln_kernel<<<512,256,0,stream>>>(
        mid, W2T + (size_t)l*65536, b2 + l*256, gn, bn, x, hb);
  }
  gemm_kernel<false,false,true><<<dim3(256,4),256,0,stream>>>(
      hb, WhT, bh, (float*)d_out, 512);
}